// Round 11
// baseline (427.527 us; speedup 1.0000x reference)
//
#include <hip/hip_runtime.h>

#define O_DIM 256
#define C_DIM 256
#define P_DIM 96
#define KHW 51
#define NSP 2601
#define WS_NEED ((size_t)O_DIM * NSP * P_DIM * 2)  // 127,844,352 B: ws[o][jl][p] bf16

typedef __attribute__((ext_vector_type(8))) short short8v;
typedef __attribute__((ext_vector_type(4))) float float4v;
typedef __attribute__((ext_vector_type(4), aligned(16))) float float4a;
typedef __attribute__((ext_vector_type(4), aligned(16))) unsigned uint4a;

static __device__ __forceinline__ unsigned f2bf(float f) {
  union { float f; unsigned u; } v; v.f = f;
  return (v.u + 0x7FFFu + ((v.u >> 16) & 1u)) >> 16;  // RNE f32->bf16
}
static __device__ __forceinline__ unsigned cvtpk(float lo, float hi) {
  unsigned r;
  asm("v_cvt_pk_bf16_f32 %0, %1, %2" : "=v"(r) : "v"(lo), "v"(hi));  // RNE pack
  return r;
}

// ---------------- K1: normalized vals (bf16) -> ws[o][jl][p], computed ONCE ----
__global__ __launch_bounds__(256) void smp_vals(
    const float* __restrict__ xg, const float* __restrict__ wc,
    const float* __restrict__ rad, unsigned* __restrict__ ws32) {
  const int b = blockIdx.x;
  const int o = b / 41;
  const int ch = b - o * 41;
  const int tid = threadIdx.x;
  const int jlloc = tid >> 2;          // 0..63
  const int sp = tid & 3;              // 24-point chunk
  const int jl = ch * 64 + jlloc;      // output-linear index
  const int jc = jl < NSP ? jl : NSP - 1;
  const int i = jc / KHW;
  const int jj = jc - i * KHW;
  const int n = jj * KHW + (KHW - 1 - i);
  const float gy = xg[n];
  const float gx = xg[NSP + n];
  const float* wp = wc + ((size_t)o * P_DIM + sp * 24) * 2;
  const float* rp = rad + (size_t)o * P_DIM + sp * 24;

  float t[24];
  int cnt = 0;
#pragma unroll
  for (int k = 0; k < 24; ++k) {
    const float prk = 1.0f / rp[k];    // r=0.5 pow2: d*prk bitwise == d/r
    float d = fabsf(wp[2 * k] - gy) + fabsf(wp[2 * k + 1] - gx);
    float s = fmaf(d, -prk, 1.0f);     // == 1 - d/r exactly
    t[k] = s > 0.0f ? s : 0.0f;
    cnt += (s > 0.0f);
  }
  cnt += __shfl_xor(cnt, 1);
  cnt += __shfl_xor(cnt, 2);
  const float inv = __builtin_amdgcn_rcpf((float)cnt + 1e-6f);

  if (jl < NSP) {
    unsigned u[12];
#pragma unroll
    for (int k = 0; k < 12; ++k) u[k] = cvtpk(t[2 * k] * inv, t[2 * k + 1] * inv);
    unsigned* dst = ws32 + (size_t)o * (NSP * 48) + jl * 48 + sp * 12;
#pragma unroll
    for (int q = 0; q < 3; ++q) {
      uint4a v = {u[q * 4], u[q * 4 + 1], u[q * 4 + 2], u[q * 4 + 3]};
      *(uint4a*)(dst + q * 4) = v;
    }
  }
}

// ---------------- K2: GEMM + complete-row buffering + contiguous 166KB burst ----
__global__ __launch_bounds__(1024, 1) void smp_gemm(
    const unsigned short* __restrict__ ws, const float* __restrict__ wts,
    float* __restrict__ out) {
  __shared__ unsigned short RBuf[16 * NSP];   // 83,232 B: complete rows, bf16

  const int b = blockIdx.x;
  const int swz = (b & 7) * 512 + (b >> 3);   // same-o blocks share an XCD
  const int o = swz >> 4;
  const int cg = swz & 15;
  const int tid = threadIdx.x;
  const int wave = tid >> 6;                  // 0..15
  const int lane = tid & 63;
  const int row16 = lane & 15;
  const int kgrp = lane >> 4;

  // A fragments: block's 16 c-rows (c = cg*16 + row16), identical across waves.
  short8v wfr[3];
  {
    const float* src = wts + ((size_t)o * C_DIM + cg * 16 + row16) * P_DIM;
#pragma unroll
    for (int ks = 0; ks < 3; ++ks) {
      const float4 a4 = *(const float4*)(src + ks * 32 + kgrp * 8);
      const float4 c4 = *(const float4*)(src + ks * 32 + kgrp * 8 + 4);
      short8v f;
      f[0] = (short)f2bf(a4.x); f[1] = (short)f2bf(a4.y);
      f[2] = (short)f2bf(a4.z); f[3] = (short)f2bf(a4.w);
      f[4] = (short)f2bf(c4.x); f[5] = (short)f2bf(c4.y);
      f[6] = (short)f2bf(c4.z); f[7] = (short)f2bf(c4.w);
      wfr[ks] = f;
    }
  }

  const unsigned short* wso = ws + (size_t)o * (NSP * P_DIM);

  // full jl sweep: 11 rounds x (16 waves x 16 jl)
  for (int r = 0; r < 11; ++r) {
    const int jlb = r * 256 + wave * 16;
    if (jlb < NSP) {
      const int jl = jlb + row16;
      const int jc = jl < NSP ? jl : NSP - 1;
      float4v acc = (float4v){0.f, 0.f, 0.f, 0.f};
#pragma unroll
      for (int ks = 0; ks < 3; ++ks) {
        const short8v bfr = *(const short8v*)(wso + (size_t)jc * P_DIM + ks * 32 + kgrp * 8);
        acc = __builtin_amdgcn_mfma_f32_16x16x32_bf16(wfr[ks], bfr, acc, 0, 0, 0);
      }
      // D: row = kgrp*4 + r2 (c-local), col = row16 (jl)
      if (jl < NSP) {
#pragma unroll
        for (int r2 = 0; r2 < 4; ++r2)
          RBuf[(kgrp * 4 + r2) * NSP + jl] = (unsigned short)f2bf(acc[r2]);
      }
    }
  }
  __syncthreads();   // rows complete

  // store phase: 16 complete rows = 166,464 B fully contiguous
  const size_t gbase = ((size_t)o * C_DIM + cg * 16) * NSP;
#pragma unroll
  for (int k = 0; k < 11; ++k) {
    const int idx4 = tid + k * 1024;        // dwordx4 index, 10404 total
    if (idx4 < 10404) {
      const uint2 u = *(const uint2*)&RBuf[idx4 * 4];
      float4a v;
      union { unsigned u; float f; } c0, c1, c2, c3;
      c0.u = (u.x & 0xFFFF0000u);  c1.u = (u.x << 16);
      c2.u = (u.y & 0xFFFF0000u);  c3.u = (u.y << 16);
      // RBuf halfwords: [0]=lo of u.x -> element 0
      v[0] = c1.f; v[1] = c0.f; v[2] = c3.f; v[3] = c2.f;
      *(float4a*)(out + gbase + (size_t)idx4 * 4) = v;
    }
  }
}

// ---------------- fallback (R7 structure) if ws too small ----------------
#define NST 41
#define PITCH 68
typedef __attribute__((ext_vector_type(4), aligned(4))) float float4u;

__global__ __launch_bounds__(256, 4) void smp_fb(
    const float* __restrict__ xg, const float* __restrict__ wc,
    const float* __restrict__ rad, const float* __restrict__ wts,
    float* __restrict__ out) {
  __shared__ float Ylds[56];
  __shared__ float pyL[96], pxL[96], prL[96];
  __shared__ __align__(16) float Sl[2][64 * PITCH];
  const int b = blockIdx.x;
  const int o = b >> 2;
  const int cq = b & 3;
  const int tid = threadIdx.x;
  const int wave = tid >> 6;
  const int lane = tid & 63;
  const int row16 = lane & 15;
  const int kgrp = lane >> 4;
  if (tid < 51) Ylds[tid] = xg[tid * KHW];
  if (tid < 96) {
    pyL[tid] = wc[((size_t)o * P_DIM + tid) * 2];
    pxL[tid] = wc[((size_t)o * P_DIM + tid) * 2 + 1];
    prL[tid] = 1.0f / rad[(size_t)o * P_DIM + tid];
  }
  short8v wfr[4][3];
  {
    const float* Wo = wts + ((size_t)o * C_DIM + cq * 64) * P_DIM;
#pragma unroll
    for (int mf = 0; mf < 4; ++mf) {
      const float* src = Wo + (mf * 16 + row16) * P_DIM;
#pragma unroll
      for (int ks = 0; ks < 3; ++ks) {
        const float4 a4 = *(const float4*)(src + ks * 32 + kgrp * 8);
        const float4 c4 = *(const float4*)(src + ks * 32 + kgrp * 8 + 4);
        short8v f;
        f[0] = (short)f2bf(a4.x); f[1] = (short)f2bf(a4.y);
        f[2] = (short)f2bf(a4.z); f[3] = (short)f2bf(a4.w);
        f[4] = (short)f2bf(c4.x); f[5] = (short)f2bf(c4.y);
        f[6] = (short)f2bf(c4.z); f[7] = (short)f2bf(c4.w);
        wfr[mf][ks] = f;
      }
    }
  }
  __syncthreads();
  const int jb = wave * 16 + row16;
  const int q = tid & 15;
  const int h = tid >> 4;
  const size_t obase = ((size_t)o * C_DIM + cq * 64) * NSP;
  for (int st = 0; st < NST; ++st) {
    const int jl = st * 64 + jb;
    const int jc = jl < NSP ? jl : NSP - 1;
    const int i = jc / KHW;
    const int jj = jc - i * KHW;
    const float gy = Ylds[jj];
    const float gx = Ylds[50 - i];
    float4v acc[4];
#pragma unroll
    for (int mf = 0; mf < 4; ++mf) acc[mf] = (float4v){0.f, 0.f, 0.f, 0.f};
    int cnt = 0;
#pragma unroll
    for (int ks = 0; ks < 3; ++ks) {
      const int pb = ks * 32 + kgrp * 8;
      const float4a py0 = *(const float4a*)&pyL[pb];
      const float4a py1 = *(const float4a*)&pyL[pb + 4];
      const float4a px0 = *(const float4a*)&pxL[pb];
      const float4a px1 = *(const float4a*)&pxL[pb + 4];
      const float4a pr0 = *(const float4a*)&prL[pb];
      const float4a pr1 = *(const float4a*)&prL[pb + 4];
      float s[8], v[8];
#pragma unroll
      for (int j = 0; j < 4; ++j) {
        s[j]     = fmaf(fabsf(py0[j] - gy) + fabsf(px0[j] - gx), -pr0[j], 1.0f);
        s[j + 4] = fmaf(fabsf(py1[j] - gy) + fabsf(px1[j] - gx), -pr1[j], 1.0f);
      }
#pragma unroll
      for (int j = 0; j < 8; ++j) {
        v[j] = s[j] > 0.0f ? s[j] : 0.0f;
        cnt += (s[j] > 0.0f);
      }
      union { unsigned u[4]; short8v sv; } bfr;
#pragma unroll
      for (int jp = 0; jp < 4; ++jp) bfr.u[jp] = cvtpk(v[2 * jp], v[2 * jp + 1]);
#pragma unroll
      for (int mf = 0; mf < 4; ++mf)
        acc[mf] = __builtin_amdgcn_mfma_f32_16x16x32_bf16(wfr[mf][ks], bfr.sv, acc[mf], 0, 0, 0);
    }
    cnt += __shfl_xor(cnt, 16);
    cnt += __shfl_xor(cnt, 32);
    const float inv = __builtin_amdgcn_rcpf((float)cnt + 1e-6f);
    float* sl = &Sl[st & 1][0];
#pragma unroll
    for (int mf = 0; mf < 4; ++mf)
#pragma unroll
      for (int r = 0; r < 4; ++r)
        sl[(mf * 16 + kgrp * 4 + r) * PITCH + jb] = acc[mf][r] * inv;
    __syncthreads();
    if (st < NST - 1) {
#pragma unroll
      for (int i2 = 0; i2 < 4; ++i2) {
        const int row = h * 4 + i2;
        const float4a vv = *(const float4a*)&sl[row * PITCH + q * 4];
        float4u sv = {vv[0], vv[1], vv[2], vv[3]};
        *(float4u*)(out + obase + (size_t)row * NSP + st * 64 + q * 4) = sv;
      }
    } else {
      const int rem = NSP - (NST - 1) * 64;
#pragma unroll
      for (int i2 = 0; i2 < 4; ++i2) {
        const int row = h * 4 + i2;
        const float4a vv = *(const float4a*)&sl[row * PITCH + q * 4];
        float* gp = out + obase + (size_t)row * NSP + st * 64 + q * 4;
        if (q * 4 + 3 < rem) {
          float4u sv = {vv[0], vv[1], vv[2], vv[3]};
          *(float4u*)gp = sv;
        } else if (q * 4 < rem) {
#pragma unroll
          for (int r2 = 0; r2 < 4; ++r2)
            if (q * 4 + r2 < rem) gp[r2] = vv[r2];
        }
      }
    }
  }
}

extern "C" void kernel_launch(void* const* d_in, const int* in_sizes, int n_in,
                              void* d_out, int out_size, void* d_ws, size_t ws_size,
                              hipStream_t stream) {
  const float* xg  = (const float*)d_in[0];
  const float* wcp = (const float*)d_in[1];
  const float* rad = (const float*)d_in[2];
  const float* wts = (const float*)d_in[3];
  float* out = (float*)d_out;
  if (ws_size >= WS_NEED) {
    hipLaunchKernelGGL(smp_vals, dim3(O_DIM * 41), dim3(256), 0, stream,
                       xg, wcp, rad, (unsigned*)d_ws);
    hipLaunchKernelGGL(smp_gemm, dim3(4096), dim3(1024), 0, stream,
                       (const unsigned short*)d_ws, wts, out);
  } else {
    hipLaunchKernelGGL(smp_fb, dim3(O_DIM * 4), dim3(256), 0, stream,
                       xg, wcp, rad, wts, out);
  }
}

// Round 12
// 384.072 us; speedup vs baseline: 1.1131x; 1.1131x over previous
//
#include <hip/hip_runtime.h>

#define O_DIM 256
#define C_DIM 256
#define P_DIM 96
#define KHW 51
#define NSP 2601       // 51*51
#define NR 11          // jl rounds: 10 full x 256 + 41-tail
#define PR 2608        // RBuf jl pitch (ushort), 16B-aligned rows

typedef __attribute__((ext_vector_type(8))) short short8v;
typedef __attribute__((ext_vector_type(4))) float float4v;
typedef __attribute__((ext_vector_type(4), aligned(16))) float float4a;
typedef __attribute__((ext_vector_type(4), aligned(4))) float float4u;

static __device__ __forceinline__ unsigned f2bf(float f) {
  union { float f; unsigned u; } v; v.f = f;
  return (v.u + 0x7FFFu + ((v.u >> 16) & 1u)) >> 16;  // RNE f32->bf16
}
static __device__ __forceinline__ unsigned cvtpk(float lo, float hi) {
  unsigned r;
  asm("v_cvt_pk_bf16_f32 %0, %1, %2" : "=v"(r) : "v"(lo), "v"(hi));  // RNE pack
  return r;
}
static __device__ __forceinline__ float bcast(unsigned u) {
  union { unsigned u; float f; } v; v.u = u; return v.f;
}

__global__ __launch_bounds__(1024, 1) void smp_fused(
    const float* __restrict__ xg,   // (1,2,51,51)
    const float* __restrict__ wc,   // (O,P,2)
    const float* __restrict__ rad,  // (O,P,1,1)
    const float* __restrict__ wts,  // (O,C,P)
    float* __restrict__ out)        // (O,C,51,51) f32
{
  __shared__ float Ylds[52];                          // ys[0..50] (== xs)
  __shared__ __align__(16) float pyL[96], pxL[96], prL[96];
  __shared__ __align__(16) unsigned short RBuf[16 * PR];  // 83.5 KB bf16 rows

  const int b = blockIdx.x;
  const int o = b >> 4;               // consecutive b -> adjacent 166KB regions
  const int cg = b & 15;
  const int tid = threadIdx.x;
  const int wave = tid >> 6;          // 0..15
  const int lane = tid & 63;
  const int row16 = lane & 15;
  const int kgrp = lane >> 4;

  // ---- one-time staging (exact input values)
  if (tid < 51) Ylds[tid] = xg[tid * KHW];            // ys[k] = x[0,0,k,0]
  if (tid < 96) {
    pyL[tid] = wc[((size_t)o * P_DIM + tid) * 2];
    pxL[tid] = wc[((size_t)o * P_DIM + tid) * 2 + 1];
    prL[tid] = 1.0f / rad[(size_t)o * P_DIM + tid];   // r=0.5 pow2: d*pr == d/r exact
  }

  // ---- A fragments: block's 16 c-rows (c = cg*16 + row16), same for all waves.
  short8v wfr[3];
  {
    const float* src = wts + ((size_t)o * C_DIM + cg * 16 + row16) * P_DIM;
#pragma unroll
    for (int ks = 0; ks < 3; ++ks) {
      const float4 a4 = *(const float4*)(src + ks * 32 + kgrp * 8);
      const float4 c4 = *(const float4*)(src + ks * 32 + kgrp * 8 + 4);
      short8v f;
      f[0] = (short)f2bf(a4.x); f[1] = (short)f2bf(a4.y);
      f[2] = (short)f2bf(a4.z); f[3] = (short)f2bf(a4.w);
      f[4] = (short)f2bf(c4.x); f[5] = (short)f2bf(c4.y);
      f[6] = (short)f2bf(c4.z); f[7] = (short)f2bf(c4.w);
      wfr[ks] = f;
    }
  }
  __syncthreads();   // staging visible

  // ---- compute: full jl sweep, vals born in-lane as MFMA B-fragments
  for (int r = 0; r < NR; ++r) {
    const int jlc = r * 256 + wave * 16 + row16;   // this lane's jl
    const int jc = jlc < NSP ? jlc : NSP - 1;
    const int i = jc / KHW;
    const int jj = jc - i * KHW;
    const float gy = Ylds[jj];        // ys[output col]
    const float gx = Ylds[50 - i];    // xs[50 - output row]

    float4v acc = (float4v){0.f, 0.f, 0.f, 0.f};
    int cnt = 0;
#pragma unroll
    for (int ks = 0; ks < 3; ++ks) {
      const int pb = ks * 32 + kgrp * 8;
      const float4a py0 = *(const float4a*)&pyL[pb];
      const float4a py1 = *(const float4a*)&pyL[pb + 4];
      const float4a px0 = *(const float4a*)&pxL[pb];
      const float4a px1 = *(const float4a*)&pxL[pb + 4];
      const float4a pr0 = *(const float4a*)&prL[pb];
      const float4a pr1 = *(const float4a*)&prL[pb + 4];
      float s[8], v[8];
#pragma unroll
      for (int j = 0; j < 4; ++j) {
        s[j]     = fmaf(fabsf(py0[j] - gy) + fabsf(px0[j] - gx), -pr0[j], 1.0f);
        s[j + 4] = fmaf(fabsf(py1[j] - gy) + fabsf(px1[j] - gx), -pr1[j], 1.0f);
      }
#pragma unroll
      for (int j = 0; j < 8; ++j) {
        v[j] = s[j] > 0.0f ? s[j] : 0.0f;
        cnt += (s[j] > 0.0f);
      }
      union { unsigned u[4]; short8v sv; } bfr;
#pragma unroll
      for (int jp = 0; jp < 4; ++jp) bfr.u[jp] = cvtpk(v[2 * jp], v[2 * jp + 1]);
      acc = __builtin_amdgcn_mfma_f32_16x16x32_bf16(wfr[ks], bfr.sv, acc, 0, 0, 0);
    }
    // count over all 96 p (4 lanes per jl share row16)
    cnt += __shfl_xor(cnt, 16);
    cnt += __shfl_xor(cnt, 32);
    const float inv = __builtin_amdgcn_rcpf((float)cnt + 1e-6f);

    // D layout: col = row16 (lane's jl), row = kgrp*4 + r2 (c-local)
    if (jlc < NSP) {
#pragma unroll
      for (int r2 = 0; r2 < 4; ++r2)
        RBuf[(kgrp * 4 + r2) * PR + jlc] = (unsigned short)f2bf(acc[r2] * inv);
    }
  }
  __syncthreads();   // all 16 rows complete

  // ---- store: 16 waves x 16 complete rows = 166,464 B fully contiguous.
  // bf16 -> f32 via <<16 (exact); validated in R10-K2 (absmax unchanged).
  {
    const unsigned short* rb = &RBuf[wave * PR];
    float* gp = out + ((size_t)o * C_DIM + cg * 16 + wave) * NSP;
#pragma unroll
    for (int it = 0; it < 10; ++it) {
      const int j = it * 256 + lane * 4;
      const uint2 u = *(const uint2*)&rb[j];
      float4u v = {bcast(u.x << 16), bcast(u.x & 0xFFFF0000u),
                   bcast(u.y << 16), bcast(u.y & 0xFFFF0000u)};
      *(float4u*)(gp + j) = v;
    }
    // tail: j = 2560 + lane*4, valid through 2600
    const int j = 2560 + lane * 4;
    if (j + 4 <= NSP) {
      const uint2 u = *(const uint2*)&rb[j];
      float4u v = {bcast(u.x << 16), bcast(u.x & 0xFFFF0000u),
                   bcast(u.y << 16), bcast(u.y & 0xFFFF0000u)};
      *(float4u*)(gp + j) = v;
    } else if (j < NSP) {
#pragma unroll
      for (int r2 = 0; r2 < 4; ++r2)
        if (j + r2 < NSP) gp[j + r2] = bcast(((unsigned)rb[j + r2]) << 16);
    }
  }
}

extern "C" void kernel_launch(void* const* d_in, const int* in_sizes, int n_in,
                              void* d_out, int out_size, void* d_ws, size_t ws_size,
                              hipStream_t stream) {
  const float* xg  = (const float*)d_in[0];
  const float* wcp = (const float*)d_in[1];
  const float* rad = (const float*)d_in[2];
  const float* wts = (const float*)d_in[3];
  float* out = (float*)d_out;
  hipLaunchKernelGGL(smp_fused, dim3(O_DIM * 16), dim3(1024), 0, stream,
                     xg, wcp, rad, wts, out);
}